// Round 4
// baseline (29.621 us; speedup 1.0000x reference)
//
#include <hip/hip_runtime.h>

#define BB 2
#define NN 1024
#define MM 1024
#define DIN 16
#define CC 32
#define HH 32

// jax.nn.gelu default (approximate=True): 0.5*v*(1+tanh(sqrt(2/pi)*(v+0.044715 v^3)))
// tanh via exp + 1-ulp v_rcp (smooth factor; mask path stays bit-exact elsewhere)
__device__ __forceinline__ float gelu_tanh(float v) {
    float v3 = v * v * v;
    float u = 0.7978845608028654f * (v + 0.044715f * v3);
    float e = __expf(2.0f * u);                       // e^(2u)
    float t = 1.0f - 2.0f * __builtin_amdgcn_rcpf(e + 1.0f);  // tanh(u)
    return 0.5f * v * (1.0f + t);
}

// One block per (batch b, query i). 256 threads = 4 waves; 8 groups x 32 channels.
// Pass B is pure-VALU per iteration (shfl broadcasts, no LDS round-trip).
__global__ __launch_bounds__(256) void gno_fused(
    const float* __restrict__ pndata, const float* __restrict__ x_coord,
    const float* __restrict__ latq,
    const float* __restrict__ W_lift, const float* __restrict__ b_lift,
    const float* __restrict__ W1, const float* __restrict__ b1,
    const float* __restrict__ W2, const float* __restrict__ b2,
    float* __restrict__ out)
{
    const int bid = blockIdx.x;
    const int b = bid >> 10;           // M = 1024
    const int i = bid & 1023;
    const int t = threadIdx.x;
    const int lane = t & 63;
    const int wave = t >> 6;
    const int g = t >> 5;              // group 0..7
    const int c = t & 31;              // channel 0..31

    __shared__ float2 nbr_xy[NN];          // per-wave segments of 256
    __shared__ unsigned nbr_meta[NN];      // j | (inner<<10)
    __shared__ float accs[8 * CC];
    __shared__ float redf[4 * 4];
    __shared__ int kcnt[4];
    __shared__ int k1cnt[4];

    // ---- per-lane weight columns (coalesced, L2-hot after first blocks) ----
    const float w1a = W1[c];
    const float w1b = W1[HH + c];
    const float w1c = W1[2 * HH + c];
    const float w1d = W1[3 * HH + c];
    const float b1v = b1[c];
    const float b2v = b2[c];
    const float blv = b_lift[c];
    float wl[DIN];
    #pragma unroll
    for (int k = 0; k < DIN; ++k) wl[k] = W_lift[k * CC + c];
    float w2c[HH];
    #pragma unroll
    for (int h = 0; h < HH; ++h) w2c[h] = W2[h * CC + c];

    const float2 qv = ((const float2*)latq)[i];
    const float q0 = qv.x, q1 = qv.y;

    // ---- per-block min/max over N; wave w loads its own 256 points ----
    const float2* xcb = (const float2*)x_coord + b * NN;
    float2 xyc[4];
    float mn0 = 1e30f, mx0 = -1e30f, mn1 = 1e30f, mx1 = -1e30f;
    #pragma unroll
    for (int kk = 0; kk < 4; ++kk) {
        xyc[kk] = xcb[wave * 256 + kk * 64 + lane];
        mn0 = fminf(mn0, xyc[kk].x); mx0 = fmaxf(mx0, xyc[kk].x);
        mn1 = fminf(mn1, xyc[kk].y); mx1 = fmaxf(mx1, xyc[kk].y);
    }
    #pragma unroll
    for (int off = 32; off > 0; off >>= 1) {
        mn0 = fminf(mn0, __shfl_down(mn0, off));
        mx0 = fmaxf(mx0, __shfl_down(mx0, off));
        mn1 = fminf(mn1, __shfl_down(mn1, off));
        mx1 = fmaxf(mx1, __shfl_down(mx1, off));
    }
    if (lane == 0) {
        redf[wave * 4 + 0] = mn0; redf[wave * 4 + 1] = mx0;
        redf[wave * 4 + 2] = mn1; redf[wave * 4 + 3] = mx1;
    }
    __syncthreads();                                          // barrier 1
    const float Amn0 = fminf(fminf(redf[0], redf[4]),  fminf(redf[8],  redf[12]));
    const float Amx0 = fmaxf(fmaxf(redf[1], redf[5]),  fmaxf(redf[9],  redf[13]));
    const float Amn1 = fminf(fminf(redf[2], redf[6]),  fminf(redf[10], redf[14]));
    const float Amx1 = fmaxf(fmaxf(redf[3], redf[7]),  fmaxf(redf[11], redf[15]));
    // denom = (mx - mn) + 1e-12, each op rounded separately (matches numpy)
    const float den0 = __fadd_rn(__fsub_rn(Amx0, Amn0), 1e-12f);
    const float den1 = __fadd_rn(__fsub_rn(Amx1, Amn1), 1e-12f);

    const float t1 = 0.01f;   // (0.1*1)^2
    const float t2 = 0.04f;   // (0.1*2)^2

    // ---- Pass A: wave-local d2 + ballot compaction into segment [wave*256, ...) ----
    const unsigned long long lmask = (1ull << lane) - 1ull;
    int kw = 0, k1w = 0;
    #pragma unroll
    for (int kk = 0; kk < 4; ++kk) {
        const int j = wave * 256 + kk * 64 + lane;
        float r0 = __fsub_rn(__fdiv_rn(__fmul_rn(2.0f, __fsub_rn(xyc[kk].x, Amn0)), den0), 1.0f);
        float r1 = __fsub_rn(__fdiv_rn(__fmul_rn(2.0f, __fsub_rn(xyc[kk].y, Amn1)), den1), 1.0f);
        float dx = __fsub_rn(q0, r0);
        float dy = __fsub_rn(q1, r1);
        float d2 = __fadd_rn(__fmul_rn(dx, dx), __fmul_rn(dy, dy));
        bool h2 = d2 <= t2;
        bool h1 = d2 <= t1;
        unsigned long long m2 = __ballot(h2);
        unsigned long long m1 = __ballot(h1);
        if (h2) {
            int idx = wave * 256 + kw + __popcll(m2 & lmask);
            nbr_meta[idx] = (unsigned)j | (h1 ? 1024u : 0u);
            nbr_xy[idx] = make_float2(r0, r1);
        }
        kw += (int)__popcll(m2);
        k1w += (int)__popcll(m1);
    }
    if (lane == 0) { kcnt[wave] = kw; k1cnt[wave] = k1w; }
    __syncthreads();                                          // barrier 2

    const int Ks0 = kcnt[0], Ks1 = kcnt[1], Ks2 = kcnt[2], Ks3 = kcnt[3];
    const int K2 = Ks0 + Ks1 + Ks2 + Ks3;
    const int c1 = k1cnt[0] + k1cnt[1] + k1cnt[2] + k1cnt[3];
    const float inv1 = 1.0f / fmaxf((float)c1, 1.0f);   // exact, identical all lanes
    const float inv2 = 1.0f / fmaxf((float)K2, 1.0f);
    const float ci = fmaf(q1, w1d, fmaf(q0, w1c, b1v));

    // ---- Pass B: walk the 4 compact segments; pure-VALU inner loop ----
    float acc = 0.0f;
    #pragma unroll
    for (int seg = 0; seg < 4; ++seg) {
        const int Ks = (seg == 0) ? Ks0 : (seg == 1) ? Ks1 : (seg == 2) ? Ks2 : Ks3;
        const int base = seg * 256;
        const int nt = (Ks + 7) >> 3;
        for (int it = 0; it < nt; ++it) {
            const int ib = it * 8 + g;
            const bool active = ib < Ks;
            const int idx = base + (active ? ib : 0);
            const unsigned meta = nbr_meta[idx];
            const float2 xy = nbr_xy[idx];
            const int j = (int)(meta & 1023u);
            const float w = ((meta & 1024u) ? inv1 : 0.0f) + inv2;

            // issue pndata broadcast loads early; latency hides under gelu+shfl
            const float4* pd4 = (const float4*)&pndata[(b * NN + j) * DIN];
            float4 pA = pd4[0], pB = pd4[1], pC = pd4[2], pD = pd4[3];

            // hidden unit h=c for this neighbor; broadcast within 32-lane group
            float pre = fmaf(xy.y, w1b, fmaf(xy.x, w1a, ci));
            float myh = gelu_tanh(pre);

            float p0 = b2v, p1 = 0.0f, p2 = 0.0f, p3 = 0.0f;
            #pragma unroll
            for (int h = 0; h < 8; ++h) {
                p0 = fmaf(__shfl(myh, h,      32), w2c[h],      p0);
                p1 = fmaf(__shfl(myh, h + 8,  32), w2c[h + 8],  p1);
                p2 = fmaf(__shfl(myh, h + 16, 32), w2c[h + 16], p2);
                p3 = fmaf(__shfl(myh, h + 24, 32), w2c[h + 24], p3);
            }
            float kc = (p0 + p1) + (p2 + p3);

            // lifting f[j][c] on the fly, 2 partial chains
            float f0 = blv, f1 = 0.0f;
            f0 = fmaf(pA.x, wl[0],  f0); f1 = fmaf(pA.y, wl[1],  f1);
            f0 = fmaf(pA.z, wl[2],  f0); f1 = fmaf(pA.w, wl[3],  f1);
            f0 = fmaf(pB.x, wl[4],  f0); f1 = fmaf(pB.y, wl[5],  f1);
            f0 = fmaf(pB.z, wl[6],  f0); f1 = fmaf(pB.w, wl[7],  f1);
            f0 = fmaf(pC.x, wl[8],  f0); f1 = fmaf(pC.y, wl[9],  f1);
            f0 = fmaf(pC.z, wl[10], f0); f1 = fmaf(pC.w, wl[11], f1);
            f0 = fmaf(pD.x, wl[12], f0); f1 = fmaf(pD.y, wl[13], f1);
            f0 = fmaf(pD.z, wl[14], f0); f1 = fmaf(pD.w, wl[15], f1);
            float fv = f0 + f1;

            if (active) acc = fmaf(w, kc * fv, acc);
        }
    }
    accs[g * CC + c] = acc;
    __syncthreads();                                          // barrier 3
    if (t < CC) {
        float s = 0.0f;
        #pragma unroll
        for (int g2 = 0; g2 < 8; ++g2) s += accs[g2 * CC + t];
        out[(b * MM + i) * CC + t] = s;
    }
}

extern "C" void kernel_launch(void* const* d_in, const int* in_sizes, int n_in,
                              void* d_out, int out_size, void* d_ws, size_t ws_size,
                              hipStream_t stream) {
    const float* pndata = (const float*)d_in[0];   // [B,N,16]
    const float* x_coord = (const float*)d_in[1];  // [B,N,2]
    const float* latq = (const float*)d_in[2];     // [M,2]
    const float* W_lift = (const float*)d_in[3];   // [16,32]
    const float* b_lift = (const float*)d_in[4];   // [32]
    const float* W1 = (const float*)d_in[5];       // [4,32]
    const float* b1 = (const float*)d_in[6];       // [32]
    const float* W2 = (const float*)d_in[7];       // [32,32]
    const float* b2 = (const float*)d_in[8];       // [32]
    float* out = (float*)d_out;                    // [B,M,32]

    gno_fused<<<BB * MM, 256, 0, stream>>>(pndata, x_coord, latq,
                                           W_lift, b_lift, W1, b1, W2, b2, out);
}

// Round 5
// 18.661 us; speedup vs baseline: 1.5873x; 1.5873x over previous
//
#include <hip/hip_runtime.h>

#define BB 2
#define NN 1024
#define MM 1024
#define DIN 16
#define CC 32
#define HH 32

// jax.nn.gelu approximate=True; tanh via exp + 1-ulp v_rcp (smooth path only)
__device__ __forceinline__ float gelu_tanh(float v) {
    float v3 = v * v * v;
    float u = 0.7978845608028654f * (v + 0.044715f * v3);
    float e = __expf(2.0f * u);
    float t = 1.0f - 2.0f * __builtin_amdgcn_rcpf(e + 1.0f);
    return 0.5f * v * (1.0f + t);
}

// One block per (batch b, query-pair). 256 threads = 4 waves; 8 groups of 32:
// groups 0-3 -> query i0, groups 4-7 -> query i0+1.
__global__ __launch_bounds__(256) void gno_fused(
    const float* __restrict__ pndata, const float* __restrict__ x_coord,
    const float* __restrict__ latq,
    const float* __restrict__ W_lift, const float* __restrict__ b_lift,
    const float* __restrict__ W1, const float* __restrict__ b1,
    const float* __restrict__ W2, const float* __restrict__ b2,
    float* __restrict__ out)
{
    const int bid = blockIdx.x;        // 1024 blocks
    const int b = bid >> 9;
    const int ipair = bid & 511;
    const int i0 = ipair * 2;
    const int t = threadIdx.x;
    const int lane = t & 63;
    const int wave = t >> 6;
    const int g = t >> 5;              // group 0..7
    const int c = t & 31;              // channel 0..31
    const int qi = g >> 2;             // query select 0/1 (group-uniform)
    const int sg = g & 3;              // subgroup within query 0..3

    __shared__ float2 xs[NN];              // rescaled coords, indexed by j (shared by both queries)
    __shared__ unsigned meta[2][NN];       // per-query compact lists (per-wave segments of 256)
    __shared__ __align__(16) float hbuf[8 * HH];
    __shared__ float accs[8 * CC];
    __shared__ float redf[16];
    __shared__ int kcnt[2][4];
    __shared__ int k1cnt[2][4];

    // ---- per-lane weight columns (coalesced 128B segments, L2-hot) ----
    const float w1a = W1[c];
    const float w1b = W1[HH + c];
    const float w1c = W1[2 * HH + c];
    const float w1d = W1[3 * HH + c];
    const float b1v = b1[c];
    const float b2v = b2[c];
    const float blv = b_lift[c];
    float wl[DIN];
    #pragma unroll
    for (int k = 0; k < DIN; ++k) wl[k] = W_lift[k * CC + c];
    float w2c[HH];
    #pragma unroll
    for (int h = 0; h < HH; ++h) w2c[h] = W2[h * CC + c];

    // two queries' coords: i0 even -> 16B aligned float4
    const float4 qq = *((const float4*)&latq[2 * i0]);   // (q0x,q0y,q1x,q1y)

    // ---- per-block min/max over N; wave w owns points [wave*256, wave*256+256) ----
    const float2* xcb = (const float2*)x_coord + b * NN;
    float2 xyc[4];
    float mn0 = 1e30f, mx0 = -1e30f, mn1 = 1e30f, mx1 = -1e30f;
    #pragma unroll
    for (int kk = 0; kk < 4; ++kk) {
        xyc[kk] = xcb[wave * 256 + kk * 64 + lane];
        mn0 = fminf(mn0, xyc[kk].x); mx0 = fmaxf(mx0, xyc[kk].x);
        mn1 = fminf(mn1, xyc[kk].y); mx1 = fmaxf(mx1, xyc[kk].y);
    }
    #pragma unroll
    for (int off = 32; off > 0; off >>= 1) {
        mn0 = fminf(mn0, __shfl_down(mn0, off));
        mx0 = fmaxf(mx0, __shfl_down(mx0, off));
        mn1 = fminf(mn1, __shfl_down(mn1, off));
        mx1 = fmaxf(mx1, __shfl_down(mx1, off));
    }
    if (lane == 0) {
        redf[wave * 4 + 0] = mn0; redf[wave * 4 + 1] = mx0;
        redf[wave * 4 + 2] = mn1; redf[wave * 4 + 3] = mx1;
    }
    __syncthreads();                                          // barrier 1
    const float Amn0 = fminf(fminf(redf[0], redf[4]),  fminf(redf[8],  redf[12]));
    const float Amx0 = fmaxf(fmaxf(redf[1], redf[5]),  fmaxf(redf[9],  redf[13]));
    const float Amn1 = fminf(fminf(redf[2], redf[6]),  fminf(redf[10], redf[14]));
    const float Amx1 = fmaxf(fmaxf(redf[3], redf[7]),  fmaxf(redf[11], redf[15]));
    // denom = (mx - mn) + 1e-12, each op rounded separately (matches numpy)
    const float den0 = __fadd_rn(__fsub_rn(Amx0, Amn0), 1e-12f);
    const float den1 = __fadd_rn(__fsub_rn(Amx1, Amn1), 1e-12f);

    const float t1 = 0.01f;   // (0.1*1)^2
    const float t2 = 0.04f;   // (0.1*2)^2

    // ---- Pass A: rescale -> xs; d2 + ballot compaction for BOTH queries ----
    const unsigned long long lmask = (1ull << lane) - 1ull;
    int kw0 = 0, k1w0 = 0, kw1 = 0, k1w1 = 0;
    #pragma unroll
    for (int kk = 0; kk < 4; ++kk) {
        const int j = wave * 256 + kk * 64 + lane;
        float r0 = __fsub_rn(__fdiv_rn(__fmul_rn(2.0f, __fsub_rn(xyc[kk].x, Amn0)), den0), 1.0f);
        float r1 = __fsub_rn(__fdiv_rn(__fmul_rn(2.0f, __fsub_rn(xyc[kk].y, Amn1)), den1), 1.0f);
        xs[j] = make_float2(r0, r1);
        // query 0
        {
            float dx = __fsub_rn(qq.x, r0);
            float dy = __fsub_rn(qq.y, r1);
            float d2 = __fadd_rn(__fmul_rn(dx, dx), __fmul_rn(dy, dy));
            bool h2 = d2 <= t2, h1 = d2 <= t1;
            unsigned long long m2 = __ballot(h2);
            unsigned long long m1 = __ballot(h1);
            if (h2) meta[0][wave * 256 + kw0 + __popcll(m2 & lmask)] =
                        (unsigned)j | (h1 ? 1024u : 0u);
            kw0 += (int)__popcll(m2);
            k1w0 += (int)__popcll(m1);
        }
        // query 1
        {
            float dx = __fsub_rn(qq.z, r0);
            float dy = __fsub_rn(qq.w, r1);
            float d2 = __fadd_rn(__fmul_rn(dx, dx), __fmul_rn(dy, dy));
            bool h2 = d2 <= t2, h1 = d2 <= t1;
            unsigned long long m2 = __ballot(h2);
            unsigned long long m1 = __ballot(h1);
            if (h2) meta[1][wave * 256 + kw1 + __popcll(m2 & lmask)] =
                        (unsigned)j | (h1 ? 1024u : 0u);
            kw1 += (int)__popcll(m2);
            k1w1 += (int)__popcll(m1);
        }
    }
    if (lane == 0) {
        kcnt[0][wave] = kw0; k1cnt[0][wave] = k1w0;
        kcnt[1][wave] = kw1; k1cnt[1][wave] = k1w1;
    }
    __syncthreads();                                          // barrier 2

    // per-query normalizers (group-uniform selects, no divergence)
    const int Ks0 = kcnt[qi][0], Ks1 = kcnt[qi][1], Ks2 = kcnt[qi][2], Ks3 = kcnt[qi][3];
    const int K2 = Ks0 + Ks1 + Ks2 + Ks3;
    const int c1 = k1cnt[qi][0] + k1cnt[qi][1] + k1cnt[qi][2] + k1cnt[qi][3];
    const float inv1 = 1.0f / fmaxf((float)c1, 1.0f);   // exact div, lane-identical
    const float inv2 = 1.0f / fmaxf((float)K2, 1.0f);
    const float qx = qi ? qq.z : qq.x;
    const float qy = qi ? qq.w : qq.y;
    const float ci = fmaf(qy, w1d, fmaf(qx, w1c, b1v));

    // ---- Pass B: 4 subgroups walk this query's 4 compact segments ----
    float acc = 0.0f;
    #pragma unroll
    for (int seg = 0; seg < 4; ++seg) {
        const int Ks = (seg == 0) ? Ks0 : (seg == 1) ? Ks1 : (seg == 2) ? Ks2 : Ks3;
        const int base = seg * 256;
        const int nt = (Ks + 3) >> 2;
        for (int it = 0; it < nt; ++it) {
            const int ib = it * 4 + sg;
            const bool active = ib < Ks;
            const unsigned m = meta[qi][base + (active ? ib : 0)];
            const int j = (int)(m & 1023u);
            const float w = ((m & 1024u) ? inv1 : 0.0f) + inv2;

            // prefetch pndata broadcast loads; latency hides under gelu + kc chain
            const float4* pd4 = (const float4*)&pndata[(b * NN + j) * DIN];
            float4 pA = pd4[0], pB = pd4[1], pC = pd4[2], pD = pd4[3];

            const float2 xy = xs[j];
            float pre = fmaf(xy.y, w1b, fmaf(xy.x, w1a, ci));
            hbuf[g * HH + c] = gelu_tanh(pre);    // same-wave LDS, in-order pipe

            float p0 = b2v, p1 = 0.0f, p2 = 0.0f, p3 = 0.0f;
            const float4* hb4 = (const float4*)&hbuf[g * HH];
            #pragma unroll
            for (int hh = 0; hh < 2; ++hh) {
                float4 h0 = hb4[hh],     h1v = hb4[hh + 2],
                       h2v = hb4[hh + 4], h3v = hb4[hh + 6];
                p0 = fmaf(h0.x,  w2c[4*hh + 0],  p0); p0 = fmaf(h0.y,  w2c[4*hh + 1],  p0);
                p0 = fmaf(h0.z,  w2c[4*hh + 2],  p0); p0 = fmaf(h0.w,  w2c[4*hh + 3],  p0);
                p1 = fmaf(h1v.x, w2c[4*hh + 8],  p1); p1 = fmaf(h1v.y, w2c[4*hh + 9],  p1);
                p1 = fmaf(h1v.z, w2c[4*hh + 10], p1); p1 = fmaf(h1v.w, w2c[4*hh + 11], p1);
                p2 = fmaf(h2v.x, w2c[4*hh + 16], p2); p2 = fmaf(h2v.y, w2c[4*hh + 17], p2);
                p2 = fmaf(h2v.z, w2c[4*hh + 18], p2); p2 = fmaf(h2v.w, w2c[4*hh + 19], p2);
                p3 = fmaf(h3v.x, w2c[4*hh + 24], p3); p3 = fmaf(h3v.y, w2c[4*hh + 25], p3);
                p3 = fmaf(h3v.z, w2c[4*hh + 26], p3); p3 = fmaf(h3v.w, w2c[4*hh + 27], p3);
            }
            float kc = (p0 + p1) + (p2 + p3);

            // lifting f[j][c] on the fly, 2 partial chains
            float f0 = blv, f1 = 0.0f;
            f0 = fmaf(pA.x, wl[0],  f0); f1 = fmaf(pA.y, wl[1],  f1);
            f0 = fmaf(pA.z, wl[2],  f0); f1 = fmaf(pA.w, wl[3],  f1);
            f0 = fmaf(pB.x, wl[4],  f0); f1 = fmaf(pB.y, wl[5],  f1);
            f0 = fmaf(pB.z, wl[6],  f0); f1 = fmaf(pB.w, wl[7],  f1);
            f0 = fmaf(pC.x, wl[8],  f0); f1 = fmaf(pC.y, wl[9],  f1);
            f0 = fmaf(pC.z, wl[10], f0); f1 = fmaf(pC.w, wl[11], f1);
            f0 = fmaf(pD.x, wl[12], f0); f1 = fmaf(pD.y, wl[13], f1);
            f0 = fmaf(pD.z, wl[14], f0); f1 = fmaf(pD.w, wl[15], f1);
            float fv = f0 + f1;

            if (active) acc = fmaf(w, kc * fv, acc);
        }
    }
    accs[g * CC + c] = acc;
    __syncthreads();                                          // barrier 3
    if (t < 64) {
        const int q2 = t >> 5;       // output query
        const int cc = t & 31;
        float s = (accs[(q2 * 4 + 0) * CC + cc] + accs[(q2 * 4 + 1) * CC + cc]) +
                  (accs[(q2 * 4 + 2) * CC + cc] + accs[(q2 * 4 + 3) * CC + cc]);
        out[(b * MM + i0 + q2) * CC + cc] = s;
    }
}

extern "C" void kernel_launch(void* const* d_in, const int* in_sizes, int n_in,
                              void* d_out, int out_size, void* d_ws, size_t ws_size,
                              hipStream_t stream) {
    const float* pndata = (const float*)d_in[0];   // [B,N,16]
    const float* x_coord = (const float*)d_in[1];  // [B,N,2]
    const float* latq = (const float*)d_in[2];     // [M,2]
    const float* W_lift = (const float*)d_in[3];   // [16,32]
    const float* b_lift = (const float*)d_in[4];   // [32]
    const float* W1 = (const float*)d_in[5];       // [4,32]
    const float* b1 = (const float*)d_in[6];       // [32]
    const float* W2 = (const float*)d_in[7];       // [32,32]
    const float* b2 = (const float*)d_in[8];       // [32]
    float* out = (float*)d_out;                    // [B,M,32]

    gno_fused<<<BB * MM / 2, 256, 0, stream>>>(pndata, x_coord, latq,
                                               W_lift, b_lift, W1, b1, W2, b2, out);
}

// Round 6
// 17.539 us; speedup vs baseline: 1.6889x; 1.0640x over previous
//
#include <hip/hip_runtime.h>

#define BB 2
#define NN 1024
#define MM 1024
#define DIN 16
#define CC 32
#define HH 32

// jax.nn.gelu approximate=True; tanh via exp + 1-ulp v_rcp (smooth path only)
__device__ __forceinline__ float gelu_tanh(float v) {
    float v3 = v * v * v;
    float u = 0.7978845608028654f * (v + 0.044715f * v3);
    float e = __expf(2.0f * u);
    float t = 1.0f - 2.0f * __builtin_amdgcn_rcpf(e + 1.0f);
    return 0.5f * v * (1.0f + t);
}

// One block per (batch b, query-pair). 256 threads = 4 waves; 8 groups of 32.
// wave0,1 -> query i0 (groups 0-3); wave2,3 -> query i0+1 (groups 4-7).
// __launch_bounds__(256,4): cap VGPR at 128 so all 1024 blocks are co-resident.
__global__ __launch_bounds__(256, 4) void gno_fused(
    const float* __restrict__ pndata, const float* __restrict__ x_coord,
    const float* __restrict__ latq,
    const float* __restrict__ W_lift, const float* __restrict__ b_lift,
    const float* __restrict__ W1, const float* __restrict__ b1,
    const float* __restrict__ W2, const float* __restrict__ b2,
    float* __restrict__ out)
{
    const int bid = blockIdx.x;        // 1024 blocks
    const int b = bid >> 9;
    const int i0 = (bid & 511) * 2;
    const int t = threadIdx.x;
    const int lane = t & 63;
    const int wave = t >> 6;
    const int g = t >> 5;              // group 0..7
    const int c = t & 31;              // channel 0..31
    const int qi = g >> 2;             // query select (wave-uniform!)
    const int sg = g & 3;              // subgroup 0..3 within query

    __shared__ float2 xs[NN];                       // rescaled coords by j
    __shared__ unsigned meta[2][NN];                // per-query single compact list
    __shared__ __align__(16) float hbuf[2][8 * HH]; // double-buffered hidden vecs
    __shared__ float accs[8 * CC];
    __shared__ float redf[16];
    __shared__ int kcnt[2][4];
    __shared__ int k1cnt[2][4];

    // ---- per-lane weight columns ----
    const float w1a = W1[c];
    const float w1b = W1[HH + c];
    const float w1c = W1[2 * HH + c];
    const float w1d = W1[3 * HH + c];
    const float b1v = b1[c];
    const float b2v = b2[c];
    const float blv = b_lift[c];
    float wl[DIN];
    #pragma unroll
    for (int k = 0; k < DIN; ++k) wl[k] = W_lift[k * CC + c];
    float w2c[HH];
    #pragma unroll
    for (int h = 0; h < HH; ++h) w2c[h] = W2[h * CC + c];

    const float4 qq = *((const float4*)&latq[2 * i0]);   // (q0x,q0y,q1x,q1y)

    // ---- per-block min/max; wave w owns points [wave*256, wave*256+256) ----
    const float2* xcb = (const float2*)x_coord + b * NN;
    float2 xyc[4];
    float mn0 = 1e30f, mx0 = -1e30f, mn1 = 1e30f, mx1 = -1e30f;
    #pragma unroll
    for (int kk = 0; kk < 4; ++kk) {
        xyc[kk] = xcb[wave * 256 + kk * 64 + lane];
        mn0 = fminf(mn0, xyc[kk].x); mx0 = fmaxf(mx0, xyc[kk].x);
        mn1 = fminf(mn1, xyc[kk].y); mx1 = fmaxf(mx1, xyc[kk].y);
    }
    #pragma unroll
    for (int off = 32; off > 0; off >>= 1) {
        mn0 = fminf(mn0, __shfl_down(mn0, off));
        mx0 = fmaxf(mx0, __shfl_down(mx0, off));
        mn1 = fminf(mn1, __shfl_down(mn1, off));
        mx1 = fmaxf(mx1, __shfl_down(mx1, off));
    }
    if (lane == 0) {
        redf[wave * 4 + 0] = mn0; redf[wave * 4 + 1] = mx0;
        redf[wave * 4 + 2] = mn1; redf[wave * 4 + 3] = mx1;
    }
    __syncthreads();                                          // barrier 1
    const float Amn0 = fminf(fminf(redf[0], redf[4]),  fminf(redf[8],  redf[12]));
    const float Amx0 = fmaxf(fmaxf(redf[1], redf[5]),  fmaxf(redf[9],  redf[13]));
    const float Amn1 = fminf(fminf(redf[2], redf[6]),  fminf(redf[10], redf[14]));
    const float Amx1 = fmaxf(fmaxf(redf[3], redf[7]),  fmaxf(redf[11], redf[15]));
    const float den0 = __fadd_rn(__fsub_rn(Amx0, Amn0), 1e-12f);
    const float den1 = __fadd_rn(__fsub_rn(Amx1, Amn1), 1e-12f);

    const float t1 = 0.01f;   // (0.1*1)^2
    const float t2 = 0.04f;   // (0.1*2)^2

    // ---- Pass A phase 1: rescale -> xs, d2 hit-bits (kept in regs), wave counts ----
    const unsigned long long lmask = (1ull << lane) - 1ull;
    unsigned bit20 = 0, bit10 = 0, bit21 = 0, bit11 = 0;
    int kw0 = 0, k1w0 = 0, kw1 = 0, k1w1 = 0;
    #pragma unroll
    for (int kk = 0; kk < 4; ++kk) {
        const int j = wave * 256 + kk * 64 + lane;
        float r0 = __fsub_rn(__fdiv_rn(__fmul_rn(2.0f, __fsub_rn(xyc[kk].x, Amn0)), den0), 1.0f);
        float r1 = __fsub_rn(__fdiv_rn(__fmul_rn(2.0f, __fsub_rn(xyc[kk].y, Amn1)), den1), 1.0f);
        xs[j] = make_float2(r0, r1);
        {
            float dx = __fsub_rn(qq.x, r0), dy = __fsub_rn(qq.y, r1);
            float d2 = __fadd_rn(__fmul_rn(dx, dx), __fmul_rn(dy, dy));
            bool h2 = d2 <= t2, h1 = d2 <= t1;
            bit20 |= (h2 ? 1u : 0u) << kk;  bit10 |= (h1 ? 1u : 0u) << kk;
            kw0 += (int)__popcll(__ballot(h2));
            k1w0 += (int)__popcll(__ballot(h1));
        }
        {
            float dx = __fsub_rn(qq.z, r0), dy = __fsub_rn(qq.w, r1);
            float d2 = __fadd_rn(__fmul_rn(dx, dx), __fmul_rn(dy, dy));
            bool h2 = d2 <= t2, h1 = d2 <= t1;
            bit21 |= (h2 ? 1u : 0u) << kk;  bit11 |= (h1 ? 1u : 0u) << kk;
            kw1 += (int)__popcll(__ballot(h2));
            k1w1 += (int)__popcll(__ballot(h1));
        }
    }
    if (lane == 0) {
        kcnt[0][wave] = kw0; k1cnt[0][wave] = k1w0;
        kcnt[1][wave] = kw1; k1cnt[1][wave] = k1w1;
    }
    __syncthreads();                                          // barrier 2

    // ---- Pass A phase 2: store into single per-query compact list ----
    int base0 = 0, base1 = 0;
    if (wave > 0) { base0 += kcnt[0][0]; base1 += kcnt[1][0]; }
    if (wave > 1) { base0 += kcnt[0][1]; base1 += kcnt[1][1]; }
    if (wave > 2) { base0 += kcnt[0][2]; base1 += kcnt[1][2]; }
    #pragma unroll
    for (int kk = 0; kk < 4; ++kk) {
        const int j = wave * 256 + kk * 64 + lane;
        {
            bool h2 = (bit20 >> kk) & 1u;
            unsigned long long m2 = __ballot(h2);
            if (h2) meta[0][base0 + (int)__popcll(m2 & lmask)] =
                        (unsigned)j | (((bit10 >> kk) & 1u) << 10);
            base0 += (int)__popcll(m2);
        }
        {
            bool h2 = (bit21 >> kk) & 1u;
            unsigned long long m2 = __ballot(h2);
            if (h2) meta[1][base1 + (int)__popcll(m2 & lmask)] =
                        (unsigned)j | (((bit11 >> kk) & 1u) << 10);
            base1 += (int)__popcll(m2);
        }
    }
    __syncthreads();                                          // barrier 3

    const int K  = kcnt[qi][0] + kcnt[qi][1] + kcnt[qi][2] + kcnt[qi][3];
    const int c1 = k1cnt[qi][0] + k1cnt[qi][1] + k1cnt[qi][2] + k1cnt[qi][3];
    const float inv1 = 1.0f / fmaxf((float)c1, 1.0f);   // exact, lane-identical
    const float inv2 = 1.0f / fmaxf((float)K, 1.0f);
    const float qx = qi ? qq.z : qq.x;
    const float qy = qi ? qq.w : qq.y;
    const float ci = fmaf(qy, w1d, fmaf(qx, w1c, b1v));

    // ---- Pass B: pipelined walk; hbuf written one iter ahead (no LDS RAW stall) ----
    float acc = 0.0f;
    const int nt = (K + 3) >> 2;
    if (nt > 0) {
        // prologue: neighbor (it=0) h -> hbuf[0]; carry its meta in regs
        bool act = sg < K;
        unsigned m = meta[qi][act ? sg : 0];
        int j = (int)(m & 1023u);
        float wgt = ((m & 1024u) ? inv1 : 0.0f) + inv2;
        {
            float2 xy = xs[j];
            float hv = gelu_tanh(fmaf(xy.y, w1b, fmaf(xy.x, w1a, ci)));
            hbuf[0][g * HH + c] = hv;
        }
        for (int it = 0; it < nt; ++it) {
            const int p = it & 1;
            // current neighbor's pndata (group-uniform broadcast loads, L2-hot)
            const float4* pd4 = (const float4*)&pndata[(b * NN + j) * DIN];
            float4 pA = pd4[0], pB4 = pd4[1], pC = pd4[2], pD = pd4[3];

            // read current hidden vector (written one full iteration ago)
            const float4* hb4 = (const float4*)&hbuf[p][g * HH];
            float4 h0 = hb4[0], h1v = hb4[1], h2v = hb4[2], h3v = hb4[3];
            float4 h4 = hb4[4], h5v = hb4[5], h6v = hb4[6], h7v = hb4[7];

            // prepare NEXT neighbor: meta, h -> hbuf[1-p] (independent work)
            bool actn = false; unsigned mn = 0; int jn = 0; float wgtn = 0.0f;
            if (it + 1 < nt) {
                const int ibn = (it + 1) * 4 + sg;
                actn = ibn < K;
                mn = meta[qi][actn ? ibn : 0];
                jn = (int)(mn & 1023u);
                wgtn = ((mn & 1024u) ? inv1 : 0.0f) + inv2;
                float2 xyn = xs[jn];
                float hn = gelu_tanh(fmaf(xyn.y, w1b, fmaf(xyn.x, w1a, ci)));
                hbuf[1 - p][g * HH + c] = hn;
            }

            // kc = h . W2[:,c] (4 partial chains)
            float p0 = b2v, p1 = 0.0f, p2 = 0.0f, p3 = 0.0f;
            p0 = fmaf(h0.x,  w2c[0],  p0); p0 = fmaf(h0.y,  w2c[1],  p0);
            p0 = fmaf(h0.z,  w2c[2],  p0); p0 = fmaf(h0.w,  w2c[3],  p0);
            p1 = fmaf(h1v.x, w2c[4],  p1); p1 = fmaf(h1v.y, w2c[5],  p1);
            p1 = fmaf(h1v.z, w2c[6],  p1); p1 = fmaf(h1v.w, w2c[7],  p1);
            p2 = fmaf(h2v.x, w2c[8],  p2); p2 = fmaf(h2v.y, w2c[9],  p2);
            p2 = fmaf(h2v.z, w2c[10], p2); p2 = fmaf(h2v.w, w2c[11], p2);
            p3 = fmaf(h3v.x, w2c[12], p3); p3 = fmaf(h3v.y, w2c[13], p3);
            p3 = fmaf(h3v.z, w2c[14], p3); p3 = fmaf(h3v.w, w2c[15], p3);
            p0 = fmaf(h4.x,  w2c[16], p0); p0 = fmaf(h4.y,  w2c[17], p0);
            p0 = fmaf(h4.z,  w2c[18], p0); p0 = fmaf(h4.w,  w2c[19], p0);
            p1 = fmaf(h5v.x, w2c[20], p1); p1 = fmaf(h5v.y, w2c[21], p1);
            p1 = fmaf(h5v.z, w2c[22], p1); p1 = fmaf(h5v.w, w2c[23], p1);
            p2 = fmaf(h6v.x, w2c[24], p2); p2 = fmaf(h6v.y, w2c[25], p2);
            p2 = fmaf(h6v.z, w2c[26], p2); p2 = fmaf(h6v.w, w2c[27], p2);
            p3 = fmaf(h7v.x, w2c[28], p3); p3 = fmaf(h7v.y, w2c[29], p3);
            p3 = fmaf(h7v.z, w2c[30], p3); p3 = fmaf(h7v.w, w2c[31], p3);
            float kc = (p0 + p1) + (p2 + p3);

            // lifting f[j][c], 2 partial chains
            float f0 = blv, f1 = 0.0f;
            f0 = fmaf(pA.x, wl[0],  f0); f1 = fmaf(pA.y, wl[1],  f1);
            f0 = fmaf(pA.z, wl[2],  f0); f1 = fmaf(pA.w, wl[3],  f1);
            f0 = fmaf(pB4.x, wl[4], f0); f1 = fmaf(pB4.y, wl[5], f1);
            f0 = fmaf(pB4.z, wl[6], f0); f1 = fmaf(pB4.w, wl[7], f1);
            f0 = fmaf(pC.x, wl[8],  f0); f1 = fmaf(pC.y, wl[9],  f1);
            f0 = fmaf(pC.z, wl[10], f0); f1 = fmaf(pC.w, wl[11], f1);
            f0 = fmaf(pD.x, wl[12], f0); f1 = fmaf(pD.y, wl[13], f1);
            f0 = fmaf(pD.z, wl[14], f0); f1 = fmaf(pD.w, wl[15], f1);
            float fv = f0 + f1;

            if (act) acc = fmaf(wgt, kc * fv, acc);

            act = actn; m = mn; j = jn; wgt = wgtn;   // rotate carried state
        }
    }
    accs[g * CC + c] = acc;
    __syncthreads();                                          // barrier 4
    if (t < 64) {
        const int q2 = t >> 5;
        const int cc = t & 31;
        float s = (accs[(q2 * 4 + 0) * CC + cc] + accs[(q2 * 4 + 1) * CC + cc]) +
                  (accs[(q2 * 4 + 2) * CC + cc] + accs[(q2 * 4 + 3) * CC + cc]);
        out[(b * MM + i0 + q2) * CC + cc] = s;
    }
}

extern "C" void kernel_launch(void* const* d_in, const int* in_sizes, int n_in,
                              void* d_out, int out_size, void* d_ws, size_t ws_size,
                              hipStream_t stream) {
    const float* pndata = (const float*)d_in[0];   // [B,N,16]
    const float* x_coord = (const float*)d_in[1];  // [B,N,2]
    const float* latq = (const float*)d_in[2];     // [M,2]
    const float* W_lift = (const float*)d_in[3];   // [16,32]
    const float* b_lift = (const float*)d_in[4];   // [32]
    const float* W1 = (const float*)d_in[5];       // [4,32]
    const float* b1 = (const float*)d_in[6];       // [32]
    const float* W2 = (const float*)d_in[7];       // [32,32]
    const float* b2 = (const float*)d_in[8];       // [32]
    float* out = (float*)d_out;                    // [B,M,32]

    gno_fused<<<BB * MM / 2, 256, 0, stream>>>(pndata, x_coord, latq,
                                               W_lift, b_lift, W1, b1, W2, b2, out);
}